// Round 4
// baseline (11525.727 us; speedup 1.0000x reference)
//
#include <hip/hip_runtime.h>
#include <hip/hip_bf16.h>

#define VOCAB 32000
#define EMBED 512
#define ENCD  512
#define HID   1024
#define ATTN  128
#define SRC   1024
#define TGT   512
#define NB    64          // persistent-kernel blocks

typedef __hip_bfloat16 bf16;
typedef _Float16 f16;
typedef __attribute__((ext_vector_type(2))) _Float16 f16x2;
typedef __attribute__((ext_vector_type(8))) _Float16 f16x8;
typedef __attribute__((ext_vector_type(8))) short bf16x8v;
typedef __attribute__((ext_vector_type(4))) float f32x4;

// ---- workspace layout (float offsets), ~25.3 MB ----
#define OFF_ENCPROJ 0           // f32 [1024][128]
#define OFF_WAHT    131072      // f32 [1024][128] Wa_h^T
#define OFF_G       262144      // f32 [512][4096] emb-part of gates + biases
#define OFF_HH      2359296     // f32 [513][1024] h history
#define OFF_INVDEN  2884608     // f32 [512]
#define OFF_CTXP    2885120     // f32 [64][512] ctx partials
#define OFF_DENP    2917888     // f32 [64] (+pad)
#define OFF_WAHP    2918016     // f32 [64][128] wah partials
#define OFF_SLOTS   2926208     // u32 [64] barrier slots (+pad)
#define OFF_WHH     2926336     // f16 [4096][1024] permuted
#define OFF_WIHC    5023488     // f16 [4096][512]  permuted
#define OFF_ENCH    6072064     // f16 [1024][512]

__device__ __forceinline__ float sigm(float x){ return 1.f/(1.f+__expf(-x)); }
__device__ __forceinline__ float tanh_f(float x){
  float ax = fabsf(x);
  float e = __expf(-2.f*ax);
  float r = (1.f - e) / (1.f + e);
  return copysignf(r, x);
}
__device__ __forceinline__ short f2bs(float x){
  union { bf16 h; short s; } u; u.h = __float2bfloat16(x); return u.s;
}
__device__ __forceinline__ bf16x8v cvt8(const float* p){
  float4 a = *reinterpret_cast<const float4*>(p);
  float4 b = *reinterpret_cast<const float4*>(p+4);
  bf16x8v r;
  r[0]=f2bs(a.x); r[1]=f2bs(a.y); r[2]=f2bs(a.z); r[3]=f2bs(a.w);
  r[4]=f2bs(b.x); r[5]=f2bs(b.y); r[6]=f2bs(b.z); r[7]=f2bs(b.w);
  return r;
}

// ---- grid barrier: per-block slots, monotone phase ids ----
__device__ __forceinline__ void gridbar(unsigned* slots, unsigned id, int b, int tid){
  __syncthreads();
  if (tid < 64){
    if (tid == 0)
      __hip_atomic_store(&slots[b], id, __ATOMIC_RELEASE, __HIP_MEMORY_SCOPE_AGENT);
    while (true){
      unsigned v = __hip_atomic_load(&slots[tid], __ATOMIC_ACQUIRE, __HIP_MEMORY_SCOPE_AGENT);
      if (__all((int)(v >= id))) break;
      __builtin_amdgcn_s_sleep(1);
    }
  }
  __syncthreads();
}

// ---- one-time: enc_proj[s][a] = enc[s]·Wa_enc[a]  (grid 64 x 128 thr) ----
__global__ void k_encproj(const float* __restrict__ enc, const float* __restrict__ Wa_enc,
                          float* __restrict__ ep){
  __shared__ float eL[16][ENCD];
  int s0 = blockIdx.x*16, tid = threadIdx.x;
  #pragma unroll
  for (int i=0;i<16;i++){
    int li = tid + i*128;
    int t = li>>7, k4 = li&127;
    *reinterpret_cast<float4*>(&eL[t][k4*4]) =
      *reinterpret_cast<const float4*>(enc + (size_t)(s0+t)*ENCD + k4*4);
  }
  __syncthreads();
  const float* w = Wa_enc + (size_t)tid*ENCD;
  float acc[16];
  #pragma unroll
  for (int t=0;t<16;t++) acc[t]=0.f;
  for (int k4=0;k4<128;k4++){
    float4 wv = *reinterpret_cast<const float4*>(w + k4*4);
    #pragma unroll
    for (int t=0;t<16;t++){
      float4 e4 = *reinterpret_cast<const float4*>(&eL[t][k4*4]);
      acc[t] += wv.x*e4.x + wv.y*e4.y + wv.z*e4.z + wv.w*e4.w;
    }
  }
  #pragma unroll
  for (int t=0;t<16;t++) ep[(size_t)(s0+t)*ATTN + tid] = acc[t];
}

// ---- one-time: transpose Wa_h (128x1024) -> WahT (1024x128) ----
__global__ void k_waht(const float* __restrict__ Wa_h, float* __restrict__ WahT){
  int idx = blockIdx.x*256 + threadIdx.x;
  int j = idx >> 7, a = idx & 127;
  WahT[idx] = Wa_h[(size_t)a*HID + j];
}

// ---- one-time: G[t][r] = b_ih[r]+b_hh[r] + W_ih[r][0:512]·emb(prev_tok(t)) ----
__global__ void k_gbase(const int* __restrict__ sos, const int* __restrict__ tgt,
                        const float* __restrict__ embt, const float* __restrict__ W_ih,
                        const float* __restrict__ b_ih, const float* __restrict__ b_hh,
                        float* __restrict__ G){
  __shared__ float eL[16][EMBED];
  int tid = threadIdx.x;
  int t0 = blockIdx.y*16;
  #pragma unroll
  for (int i=0;i<8;i++){
    int li = tid + i*256;
    int t = li>>7, k4 = li&127;
    int tg = t0 + t;
    int tok = (tg==0) ? sos[0] : tgt[tg-1];
    *reinterpret_cast<float4*>(&eL[t][k4*4]) =
      *reinterpret_cast<const float4*>(embt + (size_t)tok*EMBED + k4*4);
  }
  __syncthreads();
  int r = blockIdx.x*256 + tid;
  const float* w = W_ih + (size_t)r*(EMBED+ENCD);
  float base = b_ih[r] + b_hh[r];
  float acc[16];
  #pragma unroll
  for (int t=0;t<16;t++) acc[t]=0.f;
  for (int k4=0;k4<128;k4++){
    float4 wv = *reinterpret_cast<const float4*>(w + k4*4);
    #pragma unroll
    for (int t=0;t<16;t++){
      float4 e4 = *reinterpret_cast<const float4*>(&eL[t][k4*4]);
      acc[t] += wv.x*e4.x + wv.y*e4.y + wv.z*e4.z + wv.w*e4.w;
    }
  }
  #pragma unroll
  for (int t=0;t<16;t++) G[(size_t)(t0+t)*4096 + r] = acc[t] + base;
}

// ---- one-time conversions to f16 (permuted rows: prow = b*64 + g*16 + jj) ----
__global__ void k_cvt_whh(const float* __restrict__ W, f16* __restrict__ out){
  int r = blockIdx.x;                 // 0..4095, r = g*1024 + j
  int g = r >> 10, j = r & 1023;
  int prow = (j>>4)*64 + g*16 + (j&15);
  int k0 = threadIdx.x*8;
  float4 a = *reinterpret_cast<const float4*>(W + (size_t)r*HID + k0);
  float4 c = *reinterpret_cast<const float4*>(W + (size_t)r*HID + k0 + 4);
  f16x8 v = { (f16)a.x,(f16)a.y,(f16)a.z,(f16)a.w,(f16)c.x,(f16)c.y,(f16)c.z,(f16)c.w };
  *reinterpret_cast<f16x8*>(out + (size_t)prow*HID + k0) = v;
}
__global__ void k_cvt_wihc(const float* __restrict__ W, f16* __restrict__ out){
  int r = blockIdx.x;
  int g = r >> 10, j = r & 1023;
  int prow = (j>>4)*64 + g*16 + (j&15);
  int k0 = threadIdx.x*8;
  float4 a = *reinterpret_cast<const float4*>(W + (size_t)r*(EMBED+ENCD) + EMBED + k0);
  float4 c = *reinterpret_cast<const float4*>(W + (size_t)r*(EMBED+ENCD) + EMBED + k0 + 4);
  f16x8 v = { (f16)a.x,(f16)a.y,(f16)a.z,(f16)a.w,(f16)c.x,(f16)c.y,(f16)c.z,(f16)c.w };
  *reinterpret_cast<f16x8*>(out + (size_t)prow*ENCD + k0) = v;
}
__global__ void k_cvt_enc(const float* __restrict__ enc, f16* __restrict__ out){
  int s = blockIdx.x;
  int k0 = threadIdx.x*8;
  float4 a = *reinterpret_cast<const float4*>(enc + (size_t)s*ENCD + k0);
  float4 c = *reinterpret_cast<const float4*>(enc + (size_t)s*ENCD + k0 + 4);
  f16x8 v = { (f16)a.x,(f16)a.y,(f16)a.z,(f16)a.w,(f16)c.x,(f16)c.y,(f16)c.z,(f16)c.w };
  *reinterpret_cast<f16x8*>(out + (size_t)s*ENCD + k0) = v;
}

// ---- one-time: slots=0, Hh[0]=h0, wahp for step 0 (grid 64 x 128 thr) ----
__global__ void k_prep0(const float* __restrict__ h0, const float* __restrict__ waht,
                        float* __restrict__ Hh, float* __restrict__ wahp,
                        unsigned* __restrict__ slots){
  int b = blockIdx.x, tid = threadIdx.x;
  if (b == 0 && tid < 64) slots[tid] = 0u;
  if (b < 8) Hh[b*128 + tid] = h0[b*128 + tid];
  __shared__ float hl[16];
  if (tid < 16) hl[tid] = h0[b*16 + tid];
  __syncthreads();
  float acc = 0.f;
  #pragma unroll
  for (int jj=0;jj<16;jj++) acc += hl[jj]*waht[(size_t)(b*16+jj)*ATTN + tid];
  wahp[b*128 + tid] = acc;
}

// ---- persistent recurrence kernel: 64 blocks x 256 thr ----
__global__ __launch_bounds__(256) void k_loop(
    const f16* __restrict__ Whh_h, const f16* __restrict__ Wihc_h,
    const f16* __restrict__ enc_h, const float* __restrict__ encp,
    const float* __restrict__ waht, const float* __restrict__ G,
    float* __restrict__ Hh, float* __restrict__ Pout,
    float* __restrict__ ctxp, float* __restrict__ denp,
    float* __restrict__ wahp, float* __restrict__ invd,
    unsigned* __restrict__ slots, const float* __restrict__ c0,
    const float* __restrict__ v_a)
{
  const int b = blockIdx.x, tid = threadIdx.x;
  __shared__ f16x2 hs2[512];        // h_t as f16 pairs
  __shared__ f16x2 cs2[256];        // ctx as f16 pairs
  __shared__ float wah[128];
  __shared__ float vas[128];
  __shared__ float gacc[64];        // Whh·h for this block's 64 rows
  __shared__ float gate2[64];
  __shared__ float ps[16];
  __shared__ float cst[16];         // c state (j-slice)
  __shared__ float hnl[16];
  __shared__ float invs;

  if (tid < 128) vas[tid] = v_a[tid];
  if (tid < 16)  cst[tid] = c0[b*16 + tid];

  const int l4 = tid >> 2, q4 = tid & 3;          // row l4 (0..63), quarter q4
  const f16x8* wA = (const f16x8*)(Whh_h  + ((size_t)(b*64 + l4))*HID  + q4*256);
  const f16x8* wB = (const f16x8*)(Wihc_h + ((size_t)(b*64 + l4))*ENCD + q4*128);
  const int grow = (l4>>4)*1024 + b*16 + (l4&15); // global gate row
  const int srow = tid >> 4, sq = tid & 15;       // score mapping
  const int sg = b*16 + srow;                     // global s row

  for (int t = 0; t < TGT; ++t){
    // ---- A0: wah reduce (tid<128)  ||  h load+cvt (tid>=128) ----
    if (tid < 128){
      float acc = 0.f;
      #pragma unroll 8
      for (int p = 0; p < NB; ++p) acc += wahp[p*128 + tid];
      wah[tid] = acc;
    } else {
      int i = tid - 128;
      const float4 v0 = *reinterpret_cast<const float4*>(Hh + (size_t)t*HID + i*8);
      const float4 v1 = *reinterpret_cast<const float4*>(Hh + (size_t)t*HID + i*8 + 4);
      hs2[i*4+0] = (f16x2){(f16)v0.x,(f16)v0.y};
      hs2[i*4+1] = (f16x2){(f16)v0.z,(f16)v0.w};
      hs2[i*4+2] = (f16x2){(f16)v1.x,(f16)v1.y};
      hs2[i*4+3] = (f16x2){(f16)v1.z,(f16)v1.w};
    }
    __syncthreads();
    // ---- A1: gacc = Whh · h ----
    {
      float acc = 0.f;
      #pragma unroll 8
      for (int i = 0; i < 32; ++i){
        f16x8 wv = wA[i];
        const f16x2* wp = (const f16x2*)&wv;
        int k2 = q4*128 + i*4;
        acc = __builtin_amdgcn_fdot2(wp[0], hs2[k2+0], acc, false);
        acc = __builtin_amdgcn_fdot2(wp[1], hs2[k2+1], acc, false);
        acc = __builtin_amdgcn_fdot2(wp[2], hs2[k2+2], acc, false);
        acc = __builtin_amdgcn_fdot2(wp[3], hs2[k2+3], acc, false);
      }
      acc += __shfl_xor(acc, 1);
      acc += __shfl_xor(acc, 2);
      if (q4 == 0) gacc[l4] = acc;
    }
    // ---- A2: scores for 16 s-rows ----
    {
      const float* ep = encp + (size_t)sg*ATTN + sq*8;
      float acc = 0.f;
      #pragma unroll
      for (int u = 0; u < 8; ++u){
        int a = sq*8 + u;
        acc += vas[a] * tanh_f(ep[u] + wah[a]);
      }
      acc += __shfl_xor(acc, 1);
      acc += __shfl_xor(acc, 2);
      acc += __shfl_xor(acc, 4);
      acc += __shfl_xor(acc, 8);
      if (sq == 0){
        float pv = __expf(acc);
        ps[srow] = pv;
        Pout[(size_t)t*SRC + sg] = pv;
      }
    }
    __syncthreads();
    // ---- A3: ctx partials + den partial ----
    {
      int d2 = tid*2;
      float a0 = 0.f, a1 = 0.f;
      #pragma unroll
      for (int s = 0; s < 16; ++s){
        float pv = ps[s];
        f16x2 e2 = *reinterpret_cast<const f16x2*>(enc_h + (size_t)(b*16+s)*ENCD + d2);
        a0 += pv * (float)e2[0];
        a1 += pv * (float)e2[1];
      }
      *reinterpret_cast<float2*>(ctxp + (size_t)b*512 + d2) = make_float2(a0, a1);
      if (tid == 0){
        float ds = 0.f;
        #pragma unroll
        for (int s = 0; s < 16; ++s) ds += ps[s];
        denp[b] = ds;
      }
    }
    gridbar(slots, 2u*t+1u, b, tid);
    // ---- B0: den reduce + ctx reduce + normalize + cvt ----
    {
      if (tid < 64){
        float dv = denp[tid];
        dv += __shfl_xor(dv, 1);  dv += __shfl_xor(dv, 2);  dv += __shfl_xor(dv, 4);
        dv += __shfl_xor(dv, 8);  dv += __shfl_xor(dv, 16); dv += __shfl_xor(dv, 32);
        if (tid == 0) invs = 1.f / dv;
      }
      float a0 = 0.f, a1 = 0.f;
      #pragma unroll 8
      for (int p = 0; p < NB; ++p){
        float2 v = *reinterpret_cast<const float2*>(ctxp + (size_t)p*512 + tid*2);
        a0 += v.x; a1 += v.y;
      }
      __syncthreads();
      float inv = invs;
      cs2[tid] = (f16x2){(f16)(a0*inv), (f16)(a1*inv)};
      if (b == 0 && tid == 0) invd[t] = inv;
    }
    __syncthreads();
    // ---- B1: gates = gacc + Wihc·ctx + G ----
    {
      float acc = 0.f;
      #pragma unroll 8
      for (int i = 0; i < 16; ++i){
        f16x8 wv = wB[i];
        const f16x2* wp = (const f16x2*)&wv;
        int k2 = q4*64 + i*4;
        acc = __builtin_amdgcn_fdot2(wp[0], cs2[k2+0], acc, false);
        acc = __builtin_amdgcn_fdot2(wp[1], cs2[k2+1], acc, false);
        acc = __builtin_amdgcn_fdot2(wp[2], cs2[k2+2], acc, false);
        acc = __builtin_amdgcn_fdot2(wp[3], cs2[k2+3], acc, false);
      }
      acc += __shfl_xor(acc, 1);
      acc += __shfl_xor(acc, 2);
      if (q4 == 0) gate2[l4] = acc + gacc[l4] + G[(size_t)t*4096 + grow];
    }
    __syncthreads();
    // ---- B2: LSTM pointwise (j-slice) ----
    if (tid < 16){
      float gi = gate2[tid], gf = gate2[16+tid], gg = gate2[32+tid], go = gate2[48+tid];
      float cn = sigm(gf)*cst[tid] + sigm(gi)*tanh_f(gg);
      float hn = sigm(go)*tanh_f(cn);
      cst[tid] = cn;
      hnl[tid] = hn;
      Hh[(size_t)(t+1)*HID + b*16 + tid] = hn;
    }
    __syncthreads();
    // ---- B3: wahp partials for next step ----
    if (tid < 128){
      float acc = 0.f;
      #pragma unroll
      for (int jj = 0; jj < 16; ++jj)
        acc += hnl[jj] * waht[(size_t)(b*16+jj)*ATTN + tid];
      wahp[b*128 + tid] = acc;
    }
    gridbar(slots, 2u*t+2u, b, tid);
  }
}

// ---- epilogue: logits = H @ W_out^T + b_out (bf16 MFMA, f32 in/out) ----
__global__ __launch_bounds__(256) void k_gemm(const float* __restrict__ A, const float* __restrict__ B,
                                              const float* __restrict__ bias, float* __restrict__ C){
  int bn = blockIdx.x, bm = blockIdx.y;
  int tid = threadIdx.x;
  int wid = tid>>6, lane = tid&63;
  int wr = wid>>1, wc = wid&1;
  int rowf = lane&15, kg = lane>>4;
  const int m_base = bm*128 + wr*64;
  const int n_base = bn*128 + wc*64;
  const float* Ap = A + (size_t)(m_base + rowf)*HID + kg*8;
  const float* Bp = B + (size_t)(n_base + rowf)*HID + kg*8;
  f32x4 acc[4][4];
  #pragma unroll
  for (int i=0;i<4;i++)
    #pragma unroll
    for (int jv=0;jv<4;jv++) acc[i][jv] = (f32x4){0.f,0.f,0.f,0.f};
  for (int kk=0; kk<HID; kk+=32){
    bf16x8v av[4], bv[4];
    #pragma unroll
    for (int mt=0;mt<4;mt++) av[mt] = cvt8(Ap + (size_t)mt*16*HID + kk);
    #pragma unroll
    for (int nt=0;nt<4;nt++) bv[nt] = cvt8(Bp + (size_t)nt*16*HID + kk);
    #pragma unroll
    for (int mt=0;mt<4;mt++)
      #pragma unroll
      for (int nt=0;nt<4;nt++)
        acc[mt][nt] = __builtin_amdgcn_mfma_f32_16x16x32_bf16(av[mt], bv[nt], acc[mt][nt], 0,0,0);
  }
  #pragma unroll
  for (int mt=0;mt<4;mt++){
    #pragma unroll
    for (int nt=0;nt<4;nt++){
      int n = n_base + nt*16 + rowf;
      float bo = bias[n];
      #pragma unroll
      for (int i=0;i<4;i++){
        int m = m_base + mt*16 + kg*4 + i;
        C[(size_t)m*VOCAB + n] = acc[mt][nt][i] + bo;
      }
    }
  }
}

// ---- epilogue: attn = P * invden, in place on d_out ----
__global__ void k_attnorm(float* __restrict__ out, const float* __restrict__ invden){
  int idx = blockIdx.x*256 + threadIdx.x;
  out[idx] = out[idx]*invden[idx>>10];
}

extern "C" void kernel_launch(void* const* d_in, const int* in_sizes, int n_in,
                              void* d_out, int out_size, void* d_ws, size_t ws_size,
                              hipStream_t stream){
  const float* enc    = (const float*)d_in[0];
  const float* h0     = (const float*)d_in[1];
  const float* c0     = (const float*)d_in[2];
  const int*   sos    = (const int*)d_in[3];
  const int*   tgt    = (const int*)d_in[4];
  const float* embt   = (const float*)d_in[5];
  const float* Wa_enc = (const float*)d_in[6];
  const float* Wa_h   = (const float*)d_in[7];
  const float* v_a    = (const float*)d_in[8];
  const float* W_ih   = (const float*)d_in[9];
  const float* W_hh   = (const float*)d_in[10];
  const float* b_ih   = (const float*)d_in[11];
  const float* b_hh   = (const float*)d_in[12];
  const float* W_out  = (const float*)d_in[13];
  const float* b_out  = (const float*)d_in[14];

  float* ws    = (float*)d_ws;
  float* encp  = ws + OFF_ENCPROJ;
  float* waht  = ws + OFF_WAHT;
  float* G     = ws + OFF_G;
  float* Hh    = ws + OFF_HH;
  float* invd  = ws + OFF_INVDEN;
  float* ctxp  = ws + OFF_CTXP;
  float* denp  = ws + OFF_DENP;
  float* wahp  = ws + OFF_WAHP;
  unsigned* slots = (unsigned*)(ws + OFF_SLOTS);
  f16* Whh_h   = (f16*)(ws + OFF_WHH);
  f16* Wihc_h  = (f16*)(ws + OFF_WIHC);
  f16* enc_h   = (f16*)(ws + OFF_ENCH);

  float* out_logits = (float*)d_out;
  float* out_attn   = out_logits + (size_t)TGT*VOCAB;

  k_encproj <<<64, 128, 0, stream>>>(enc, Wa_enc, encp);
  k_waht    <<<512, 256, 0, stream>>>(Wa_h, waht);
  k_gbase   <<<dim3(16, 32), 256, 0, stream>>>(sos, tgt, embt, W_ih, b_ih, b_hh, G);
  k_cvt_whh <<<4096, 128, 0, stream>>>(W_hh, Whh_h);
  k_cvt_wihc<<<4096, 64, 0, stream>>>(W_ih, Wihc_h);
  k_cvt_enc <<<1024, 64, 0, stream>>>(enc, enc_h);
  k_prep0   <<<64, 128, 0, stream>>>(h0, waht, Hh, wahp, slots);

  k_loop<<<NB, 256, 0, stream>>>(Whh_h, Wihc_h, enc_h, encp, waht, G,
                                 Hh, out_attn, ctxp, denp, wahp, invd,
                                 slots, c0, v_a);

  k_gemm   <<<dim3(250, 4), 256, 0, stream>>>(Hh + HID, W_out, b_out, out_logits);
  k_attnorm<<<2048, 256, 0, stream>>>(out_attn, invd);
}

// Round 5
// 10703.866 us; speedup vs baseline: 1.0768x; 1.0768x over previous
//
#include <hip/hip_runtime.h>
#include <hip/hip_bf16.h>

#define VOCAB 32000
#define EMBED 512
#define ENCD  512
#define HID   1024
#define ATTN  128
#define SRC   1024
#define TGT   512
#define NB    32          // persistent-kernel blocks
#define NT    1024        // threads per block (16 waves)

typedef __hip_bfloat16 bf16;
typedef _Float16 f16;
typedef __attribute__((ext_vector_type(2))) _Float16 f16x2;
typedef __attribute__((ext_vector_type(8))) _Float16 f16x8;
typedef __attribute__((ext_vector_type(8))) short bf16x8v;
typedef __attribute__((ext_vector_type(4))) float f32x4;

// ---- workspace layout (float offsets), ~25.3 MB ----
#define OFF_ENCPROJ 0           // f32 [1024][128]
#define OFF_G       131072      // f32 [512][4096] PERMUTED gate bases (prow)
#define OFF_HH      2228224     // f32 [513][1024] h history
#define OFF_INVDEN  2753536     // f32 [512]
#define OFF_CTXP    2754048     // f32 [32][512] ctx partials
#define OFF_DENP    2770432     // f32 [32] (+pad)
#define OFF_WAHP    2770560     // f32 [32][128] wah partials
#define OFF_SLOTS   2774656     // u32 [32] barrier slots (+pad)
#define OFF_WHH     2774784     // f16 [4096][1024] permuted rows
#define OFF_WIHC    4871936     // f16 [4096][512]  permuted rows
#define OFF_ENCHT   5920512     // f16 [512][1024]  enc TRANSPOSED
// end ≈ 6182656 floats ≈ 24.7 MB

__device__ __forceinline__ float sigm(float x){ return 1.f/(1.f+__expf(-x)); }
__device__ __forceinline__ float tanh_f(float x){
  float ax = fabsf(x);
  float e = __expf(-2.f*ax);
  float r = (1.f - e) / (1.f + e);
  return copysignf(r, x);
}
__device__ __forceinline__ short f2bs(float x){
  union { bf16 h; short s; } u; u.h = __float2bfloat16(x); return u.s;
}
__device__ __forceinline__ bf16x8v cvt8(const float* p){
  float4 a = *reinterpret_cast<const float4*>(p);
  float4 b = *reinterpret_cast<const float4*>(p+4);
  bf16x8v r;
  r[0]=f2bs(a.x); r[1]=f2bs(a.y); r[2]=f2bs(a.z); r[3]=f2bs(a.w);
  r[4]=f2bs(b.x); r[5]=f2bs(b.y); r[6]=f2bs(b.z); r[7]=f2bs(b.w);
  return r;
}

// ---- grid barrier: relaxed polls, fences hoisted OUT of the spin loop ----
__device__ __forceinline__ void gridbar(unsigned* slots, unsigned id, int b, int tid){
  __syncthreads();   // all waves' stores drained (compiler emits vmcnt(0) before s_barrier)
  if (tid == 0){
    __builtin_amdgcn_fence(__ATOMIC_RELEASE, "agent");   // one wbl2, not per-poll
    __hip_atomic_store(&slots[b], id, __ATOMIC_RELAXED, __HIP_MEMORY_SCOPE_AGENT);
  }
  if (tid < 64){
    while (true){
      unsigned v = __hip_atomic_load(&slots[tid & (NB-1)], __ATOMIC_RELAXED, __HIP_MEMORY_SCOPE_AGENT);
      if (__all((int)(v >= id))) break;
      __builtin_amdgcn_s_sleep(1);
    }
    __builtin_amdgcn_fence(__ATOMIC_ACQUIRE, "agent");   // one inv, per-CU L1 + XCD L2
  }
  __syncthreads();
}

// ---- one-time: enc_proj[s][a] = enc[s]·Wa_enc[a]  (grid 64 x 128 thr) ----
__global__ void k_encproj(const float* __restrict__ enc, const float* __restrict__ Wa_enc,
                          float* __restrict__ ep){
  __shared__ float eL[16][ENCD];
  int s0 = blockIdx.x*16, tid = threadIdx.x;
  #pragma unroll
  for (int i=0;i<16;i++){
    int li = tid + i*128;
    int t = li>>7, k4 = li&127;
    *reinterpret_cast<float4*>(&eL[t][k4*4]) =
      *reinterpret_cast<const float4*>(enc + (size_t)(s0+t)*ENCD + k4*4);
  }
  __syncthreads();
  const float* w = Wa_enc + (size_t)tid*ENCD;
  float acc[16];
  #pragma unroll
  for (int t=0;t<16;t++) acc[t]=0.f;
  for (int k4=0;k4<128;k4++){
    float4 wv = *reinterpret_cast<const float4*>(w + k4*4);
    #pragma unroll
    for (int t=0;t<16;t++){
      float4 e4 = *reinterpret_cast<const float4*>(&eL[t][k4*4]);
      acc[t] += wv.x*e4.x + wv.y*e4.y + wv.z*e4.z + wv.w*e4.w;
    }
  }
  #pragma unroll
  for (int t=0;t<16;t++) ep[(size_t)(s0+t)*ATTN + tid] = acc[t];
}

// ---- one-time: Gp[t][prow] = b_ih+b_hh + W_ih[:,0:512]·emb, prow-permuted ----
__global__ void k_gbase(const int* __restrict__ sos, const int* __restrict__ tgt,
                        const float* __restrict__ embt, const float* __restrict__ W_ih,
                        const float* __restrict__ b_ih, const float* __restrict__ b_hh,
                        float* __restrict__ Gp){
  __shared__ float eL[16][EMBED];
  int tid = threadIdx.x;
  int t0 = blockIdx.y*16;
  #pragma unroll
  for (int i=0;i<8;i++){
    int li = tid + i*256;
    int t = li>>7, k4 = li&127;
    int tg = t0 + t;
    int tok = (tg==0) ? sos[0] : tgt[tg-1];
    *reinterpret_cast<float4*>(&eL[t][k4*4]) =
      *reinterpret_cast<const float4*>(embt + (size_t)tok*EMBED + k4*4);
  }
  __syncthreads();
  int r = blockIdx.x*256 + tid;
  int g = r>>10, j = r&1023;
  int prow = (j>>5)*128 + g*32 + (j&31);
  const float* w = W_ih + (size_t)r*(EMBED+ENCD);
  float base = b_ih[r] + b_hh[r];
  float acc[16];
  #pragma unroll
  for (int t=0;t<16;t++) acc[t]=0.f;
  for (int k4=0;k4<128;k4++){
    float4 wv = *reinterpret_cast<const float4*>(w + k4*4);
    #pragma unroll
    for (int t=0;t<16;t++){
      float4 e4 = *reinterpret_cast<const float4*>(&eL[t][k4*4]);
      acc[t] += wv.x*e4.x + wv.y*e4.y + wv.z*e4.z + wv.w*e4.w;
    }
  }
  #pragma unroll
  for (int t=0;t<16;t++) Gp[(size_t)(t0+t)*4096 + prow] = acc[t] + base;
}

// ---- one-time f16 conversions, permuted: prow = (j>>5)*128 + g*32 + (j&31) ----
__global__ void k_cvt_whh(const float* __restrict__ W, f16* __restrict__ out){
  int r = blockIdx.x;
  int g = r >> 10, j = r & 1023;
  int prow = (j>>5)*128 + g*32 + (j&31);
  int k0 = threadIdx.x*8;
  float4 a = *reinterpret_cast<const float4*>(W + (size_t)r*HID + k0);
  float4 c = *reinterpret_cast<const float4*>(W + (size_t)r*HID + k0 + 4);
  f16x8 v = { (f16)a.x,(f16)a.y,(f16)a.z,(f16)a.w,(f16)c.x,(f16)c.y,(f16)c.z,(f16)c.w };
  *reinterpret_cast<f16x8*>(out + (size_t)prow*HID + k0) = v;
}
__global__ void k_cvt_wihc(const float* __restrict__ W, f16* __restrict__ out){
  int r = blockIdx.x;
  int g = r >> 10, j = r & 1023;
  int prow = (j>>5)*128 + g*32 + (j&31);
  int k0 = threadIdx.x*8;
  float4 a = *reinterpret_cast<const float4*>(W + (size_t)r*(EMBED+ENCD) + EMBED + k0);
  float4 c = *reinterpret_cast<const float4*>(W + (size_t)r*(EMBED+ENCD) + EMBED + k0 + 4);
  f16x8 v = { (f16)a.x,(f16)a.y,(f16)a.z,(f16)a.w,(f16)c.x,(f16)c.y,(f16)c.z,(f16)c.w };
  *reinterpret_cast<f16x8*>(out + (size_t)prow*ENCD + k0) = v;
}
// enc [1024][512] f32 -> encT_h [512][1024] f16 (tiled transpose)
__global__ void k_cvt_encT(const float* __restrict__ enc, f16* __restrict__ out){
  __shared__ float tile[64][65];
  int s0 = blockIdx.x*64, d0 = blockIdx.y*64;
  int tid = threadIdx.x;
  #pragma unroll
  for (int i=0;i<16;i++){
    int idx = tid + i*256;
    int sl = idx>>6, dl = idx&63;
    tile[sl][dl] = enc[(size_t)(s0+sl)*ENCD + d0+dl];
  }
  __syncthreads();
  #pragma unroll
  for (int i=0;i<16;i++){
    int idx = tid + i*256;
    int dl = idx>>6, sl = idx&63;
    out[(size_t)(d0+dl)*SRC + s0+sl] = (f16)tile[sl][dl];
  }
}

// ---- one-time: slots=0, Hh[0]=h0, wahp for step 0 (grid 32 x 128 thr) ----
__global__ void k_prep0(const float* __restrict__ h0, const float* __restrict__ Wa_h,
                        float* __restrict__ Hh, float* __restrict__ wahp,
                        unsigned* __restrict__ slots){
  int b = blockIdx.x, tid = threadIdx.x;
  if (b == 0 && tid < NB) slots[tid] = 0u;
  if (b < 8) Hh[b*128 + tid] = h0[b*128 + tid];
  __shared__ float hl[32];
  if (tid < 32) hl[tid] = h0[b*32 + tid];
  __syncthreads();
  const float* wr = Wa_h + (size_t)tid*HID + b*32;
  float acc = 0.f;
  #pragma unroll
  for (int i4=0;i4<8;i4++){
    float4 w4 = *reinterpret_cast<const float4*>(wr + i4*4);
    acc += w4.x*hl[i4*4] + w4.y*hl[i4*4+1] + w4.z*hl[i4*4+2] + w4.w*hl[i4*4+3];
  }
  wahp[b*128 + tid] = acc;
}

// ---- persistent recurrence kernel: 32 blocks x 1024 thr (16 waves/CU) ----
__global__ __launch_bounds__(NT) void k_loop(
    const f16* __restrict__ Whh_h, const f16* __restrict__ Wihc_h,
    const f16* __restrict__ encT_h, const float* __restrict__ encp,
    const float* __restrict__ Wa_h, const float* __restrict__ Gp,
    float* __restrict__ Hh, float* __restrict__ Pout,
    float* __restrict__ ctxp, float* __restrict__ denp,
    float* __restrict__ wahp, float* __restrict__ invd,
    unsigned* __restrict__ slots, const float* __restrict__ c0,
    const float* __restrict__ v_a)
{
  const int b = blockIdx.x, tid = threadIdx.x;
  __shared__ f16x2 hs2[512];        // h_t as f16 pairs
  __shared__ float wp[4][128];      // wah partial sums
  __shared__ float vas[128];
  __shared__ float ps[32];          // unnormalized p for this block's rows
  __shared__ float gld[128];        // G row slice
  __shared__ float gacc[128];       // Whh·h
  __shared__ float cp2[2][512];
  __shared__ f16x2 cs2[256];        // normalized ctx as f16 pairs
  __shared__ float g2[128];
  __shared__ float cst[32];         // c state slice
  __shared__ float hnl[32];
  __shared__ float invs;

  if (tid < 128) vas[tid] = v_a[tid];
  if (tid < 32)  cst[tid] = c0[b*32 + tid];

  const int l8 = tid >> 3, q8 = tid & 7;   // matvec: 128 rows x 8 lanes
  const f16x8* wA = (const f16x8*)(Whh_h  + ((size_t)(b*128 + l8))*HID  + q8*128);
  const f16x8* wB = (const f16x8*)(Wihc_h + ((size_t)(b*128 + l8))*ENCD + q8*64);
  const int srow = tid >> 5, slq = tid & 31;   // scores: 32 rows x 32 lanes
  const int sg = b*32 + srow;

  for (int t = 0; t < TGT; ++t){
    // ---- A0: h load+cvt | wahp hierarchical reduce | G preload ----
    if (tid < 256){
      float4 v0 = *reinterpret_cast<const float4*>(Hh + (size_t)t*HID + tid*4);
      hs2[tid*2]   = (f16x2){(f16)v0.x,(f16)v0.y};
      hs2[tid*2+1] = (f16x2){(f16)v0.z,(f16)v0.w};
    } else if (tid < 768){
      int idx = tid - 256, a = idx & 127, g = idx >> 7;   // g in 0..3, 8 partials each
      float acc = 0.f;
      #pragma unroll
      for (int p = 0; p < 8; ++p) acc += wahp[(g*8+p)*128 + a];
      wp[g][a] = acc;
    } else if (tid < 896){
      gld[tid-768] = Gp[(size_t)t*4096 + b*128 + (tid-768)];
    }
    __syncthreads();
    // ---- A1: scores (32 rows, 32 lanes each, 4 attn dims/lane) ----
    {
      float4 e4 = *reinterpret_cast<const float4*>(encp + (size_t)sg*ATTN + slq*4);
      float sc = 0.f;
      #pragma unroll
      for (int u = 0; u < 4; ++u){
        int a = slq*4 + u;
        float wa = wp[0][a]+wp[1][a]+wp[2][a]+wp[3][a];
        sc += vas[a]*tanh_f((&e4.x)[u] + wa);
      }
      sc += __shfl_xor(sc,1); sc += __shfl_xor(sc,2); sc += __shfl_xor(sc,4);
      sc += __shfl_xor(sc,8); sc += __shfl_xor(sc,16);
      if (slq == 0){
        float pv = __expf(sc);
        ps[srow] = pv;
        Pout[(size_t)t*SRC + sg] = pv;
      }
    }
    __syncthreads();
    // ---- A2: ctx partials (contiguous via encT) + den partial ----
    if (tid < 512){
      const f16x8* er = (const f16x8*)(encT_h + (size_t)tid*SRC + b*32);
      float a0 = 0.f;
      #pragma unroll
      for (int i = 0; i < 4; ++i){
        f16x8 ev = er[i];
        #pragma unroll
        for (int u = 0; u < 8; ++u) a0 += ps[i*8+u] * (float)ev[u];
      }
      ctxp[b*512 + tid] = a0;
    } else if (tid < 576){
      float v = (tid < 544) ? ps[tid-512] : 0.f;
      v += __shfl_xor(v,1); v += __shfl_xor(v,2); v += __shfl_xor(v,4);
      v += __shfl_xor(v,8); v += __shfl_xor(v,16);
      if (tid == 512) denp[b] = v;
    }
    // ---- A3: gacc = Whh·h (no dependency on barrier -> hides skew) ----
    {
      float acc = 0.f;
      #pragma unroll
      for (int i = 0; i < 16; ++i){
        f16x8 wv = wA[i];
        const f16x2* wpp = (const f16x2*)&wv;
        int k2 = q8*64 + i*4;
        acc = __builtin_amdgcn_fdot2(wpp[0], hs2[k2+0], acc, false);
        acc = __builtin_amdgcn_fdot2(wpp[1], hs2[k2+1], acc, false);
        acc = __builtin_amdgcn_fdot2(wpp[2], hs2[k2+2], acc, false);
        acc = __builtin_amdgcn_fdot2(wpp[3], hs2[k2+3], acc, false);
      }
      acc += __shfl_xor(acc,1); acc += __shfl_xor(acc,2); acc += __shfl_xor(acc,4);
      if (q8 == 0) gacc[l8] = acc;
    }
    gridbar(slots, 2u*t+1u, b, tid);
    // ---- B0: den reduce + ctx reduce ----
    if (tid < 64){
      float dv = (tid < 32) ? denp[tid] : 0.f;
      dv += __shfl_xor(dv,1); dv += __shfl_xor(dv,2); dv += __shfl_xor(dv,4);
      dv += __shfl_xor(dv,8); dv += __shfl_xor(dv,16);
      if (tid == 0){ float iv = 1.f/dv; invs = iv; if (b == 0) invd[t] = iv; }
    }
    {
      int d = tid & 511, g = tid >> 9;    // 2 groups of 16 partials
      float a0 = 0.f;
      #pragma unroll
      for (int p = 0; p < 16; ++p) a0 += ctxp[(g*16+p)*512 + d];
      cp2[g][d] = a0;
    }
    __syncthreads();
    if (tid < 256){
      float inv = invs;
      int d2 = tid*2;
      cs2[tid] = (f16x2){ (f16)((cp2[0][d2]+cp2[1][d2])*inv),
                          (f16)((cp2[0][d2+1]+cp2[1][d2+1])*inv) };
    }
    __syncthreads();
    // ---- B1: gates = gacc + Wihc·ctx + G ----
    {
      float acc = 0.f;
      #pragma unroll
      for (int i = 0; i < 8; ++i){
        f16x8 wv = wB[i];
        const f16x2* wpp = (const f16x2*)&wv;
        int k2 = q8*32 + i*4;
        acc = __builtin_amdgcn_fdot2(wpp[0], cs2[k2+0], acc, false);
        acc = __builtin_amdgcn_fdot2(wpp[1], cs2[k2+1], acc, false);
        acc = __builtin_amdgcn_fdot2(wpp[2], cs2[k2+2], acc, false);
        acc = __builtin_amdgcn_fdot2(wpp[3], cs2[k2+3], acc, false);
      }
      acc += __shfl_xor(acc,1); acc += __shfl_xor(acc,2); acc += __shfl_xor(acc,4);
      if (q8 == 0) g2[l8] = acc + gacc[l8] + gld[l8];
    }
    __syncthreads();
    // ---- B2: LSTM pointwise (32 j-dims) ----
    if (tid < 32){
      float gi = g2[tid], gf = g2[32+tid], gg = g2[64+tid], go = g2[96+tid];
      float cn = sigm(gf)*cst[tid] + sigm(gi)*tanh_f(gg);
      float hn = sigm(go)*tanh_f(cn);
      cst[tid] = cn; hnl[tid] = hn;
      Hh[(size_t)(t+1)*HID + b*32 + tid] = hn;
    }
    __syncthreads();
    // ---- B3: wahp partials (Wa_h rows are contiguous over j) ----
    if (tid < 128){
      const float* wr = Wa_h + (size_t)tid*HID + b*32;
      float acc = 0.f;
      #pragma unroll
      for (int i4 = 0; i4 < 8; ++i4){
        float4 w4 = *reinterpret_cast<const float4*>(wr + i4*4);
        acc += w4.x*hnl[i4*4] + w4.y*hnl[i4*4+1] + w4.z*hnl[i4*4+2] + w4.w*hnl[i4*4+3];
      }
      wahp[b*128 + tid] = acc;
    }
    gridbar(slots, 2u*t+2u, b, tid);
  }
}

// ---- epilogue: logits = H @ W_out^T + b_out (bf16 MFMA, f32 in/out) ----
__global__ __launch_bounds__(256) void k_gemm(const float* __restrict__ A, const float* __restrict__ B,
                                              const float* __restrict__ bias, float* __restrict__ C){
  int bn = blockIdx.x, bm = blockIdx.y;
  int tid = threadIdx.x;
  int wid = tid>>6, lane = tid&63;
  int wr = wid>>1, wc = wid&1;
  int rowf = lane&15, kg = lane>>4;
  const int m_base = bm*128 + wr*64;
  const int n_base = bn*128 + wc*64;
  const float* Ap = A + (size_t)(m_base + rowf)*HID + kg*8;
  const float* Bp = B + (size_t)(n_base + rowf)*HID + kg*8;
  f32x4 acc[4][4];
  #pragma unroll
  for (int i=0;i<4;i++)
    #pragma unroll
    for (int jv=0;jv<4;jv++) acc[i][jv] = (f32x4){0.f,0.f,0.f,0.f};
  for (int kk=0; kk<HID; kk+=32){
    bf16x8v av[4], bv[4];
    #pragma unroll
    for (int mt=0;mt<4;mt++) av[mt] = cvt8(Ap + (size_t)mt*16*HID + kk);
    #pragma unroll
    for (int nt=0;nt<4;nt++) bv[nt] = cvt8(Bp + (size_t)nt*16*HID + kk);
    #pragma unroll
    for (int mt=0;mt<4;mt++)
      #pragma unroll
      for (int nt=0;nt<4;nt++)
        acc[mt][nt] = __builtin_amdgcn_mfma_f32_16x16x32_bf16(av[mt], bv[nt], acc[mt][nt], 0,0,0);
  }
  #pragma unroll
  for (int mt=0;mt<4;mt++){
    #pragma unroll
    for (int nt=0;nt<4;nt++){
      int n = n_base + nt*16 + rowf;
      float bo = bias[n];
      #pragma unroll
      for (int i=0;i<4;i++){
        int m = m_base + mt*16 + kg*4 + i;
        C[(size_t)m*VOCAB + n] = acc[mt][nt][i] + bo;
      }
    }
  }
}

// ---- epilogue: attn = P * invden, in place on d_out ----
__global__ void k_attnorm(float* __restrict__ out, const float* __restrict__ invden){
  int idx = blockIdx.x*256 + threadIdx.x;
  out[idx] = out[idx]*invden[idx>>10];
}

extern "C" void kernel_launch(void* const* d_in, const int* in_sizes, int n_in,
                              void* d_out, int out_size, void* d_ws, size_t ws_size,
                              hipStream_t stream){
  const float* enc    = (const float*)d_in[0];
  const float* h0     = (const float*)d_in[1];
  const float* c0     = (const float*)d_in[2];
  const int*   sos    = (const int*)d_in[3];
  const int*   tgt    = (const int*)d_in[4];
  const float* embt   = (const float*)d_in[5];
  const float* Wa_enc = (const float*)d_in[6];
  const float* Wa_h   = (const float*)d_in[7];
  const float* v_a    = (const float*)d_in[8];
  const float* W_ih   = (const float*)d_in[9];
  const float* W_hh   = (const float*)d_in[10];
  const float* b_ih   = (const float*)d_in[11];
  const float* b_hh   = (const float*)d_in[12];
  const float* W_out  = (const float*)d_in[13];
  const float* b_out  = (const float*)d_in[14];

  float* ws    = (float*)d_ws;
  float* encp  = ws + OFF_ENCPROJ;
  float* Gp    = ws + OFF_G;
  float* Hh    = ws + OFF_HH;
  float* invd  = ws + OFF_INVDEN;
  float* ctxp  = ws + OFF_CTXP;
  float* denp  = ws + OFF_DENP;
  float* wahp  = ws + OFF_WAHP;
  unsigned* slots = (unsigned*)(ws + OFF_SLOTS);
  f16* Whh_h   = (f16*)(ws + OFF_WHH);
  f16* Wihc_h  = (f16*)(ws + OFF_WIHC);
  f16* encT_h  = (f16*)(ws + OFF_ENCHT);

  float* out_logits = (float*)d_out;
  float* out_attn   = out_logits + (size_t)TGT*VOCAB;

  k_encproj <<<64, 128, 0, stream>>>(enc, Wa_enc, encp);
  k_gbase   <<<dim3(16, 32), 256, 0, stream>>>(sos, tgt, embt, W_ih, b_ih, b_hh, Gp);
  k_cvt_whh <<<4096, 128, 0, stream>>>(W_hh, Whh_h);
  k_cvt_wihc<<<4096, 64, 0, stream>>>(W_ih, Wihc_h);
  k_cvt_encT<<<dim3(16, 8), 256, 0, stream>>>(enc, encT_h);
  k_prep0   <<<NB, 128, 0, stream>>>(h0, Wa_h, Hh, wahp, slots);

  k_loop<<<NB, NT, 0, stream>>>(Whh_h, Wihc_h, encT_h, encp, Wa_h, Gp,
                                Hh, out_attn, ctxp, denp, wahp, invd,
                                slots, c0, v_a);

  k_gemm   <<<dim3(250, 4), 256, 0, stream>>>(Hh + HID, W_out, b_out, out_logits);
  k_attnorm<<<2048, 256, 0, stream>>>(out_attn, invd);
}